// Round 1
// baseline (101.556 us; speedup 1.0000x reference)
//
#include <hip/hip_runtime.h>
#include <hip/hip_bf16.h>

// RNN_73048803770905: fused [B,T,200]x[200,64] projection + 128-step tanh RNN + sigmoid head.
// B=4096, T=128, D_IN=200, H=64. HBM-bound (419 MB x read, floor ~67us).
// 256 blocks x 256 thr; block = 16 batch rows; MFMA 16x16x32 bf16 for both GEMMs.

#define TSEQ 128
#define DIN  200
#define HID  64
#define NB   16
#define TC   4
#define NCH  (TSEQ/TC)

typedef short bf16x8 __attribute__((ext_vector_type(8)));
typedef float f32x4  __attribute__((ext_vector_type(4)));

__device__ __forceinline__ short f2bf(float f) {
  __hip_bfloat16 h = __float2bfloat16(f);
  return __builtin_bit_cast(short, h);
}
__device__ __forceinline__ bf16x8 cvt8(f32x4 a, f32x4 b) {
  bf16x8 r;
#pragma unroll
  for (int i = 0; i < 4; ++i) { r[i] = f2bf(a[i]); r[4 + i] = f2bf(b[i]); }
  return r;
}
__device__ __forceinline__ float fast_tanh(float x) {
  x = fminf(10.f, fmaxf(-10.f, x));
  float e = __expf(2.f * x);
  return (e - 1.f) * __builtin_amdgcn_rcpf(e + 1.f);
}
// Raw barrier: LDS-ordering only; leaves vmcnt outstanding so prefetched x loads
// stay in flight across the recurrence phase (guide §5 8-phase pattern).
__device__ __forceinline__ void barrier_lds() {
  asm volatile("s_waitcnt lgkmcnt(0)" ::: "memory");
  __builtin_amdgcn_s_barrier();
  asm volatile("" ::: "memory");
}

__global__ __launch_bounds__(256, 1) void rnn_fused(
    const float* __restrict__ x,   const float* __restrict__ Wih,
    const float* __restrict__ Whh, const float* __restrict__ bih,
    const float* __restrict__ bhh, const float* __restrict__ Wout,
    const float* __restrict__ bout, float* __restrict__ out)
{
  __shared__ float          xp[TC][NB][68];       // xp chunk, f32; also final-H f32 at end
  __shared__ unsigned short hbuf[2][NB][72];      // h state double buffer, bf16 bits

  const int tid  = threadIdx.x;
  const int w    = tid >> 6;      // wave 0..3
  const int lane = tid & 63;
  const int m    = lane & 15;     // MFMA row/col-in-tile index
  const int g    = lane >> 4;     // 16-lane group 0..3
  const int b0   = blockIdx.x * NB;

  // ---- prologue: prefetch chunk 0 (this wave's timestep t = w) ----
  f32x4 pre[7][2];
  {
    const float* xrow = x + ((size_t)(b0 + m) * TSEQ + w) * DIN;
#pragma unroll
    for (int ks = 0; ks < 7; ++ks) {
      const int d = ks * 32 + g * 8;
      if (d < DIN) {
        pre[ks][0] = *reinterpret_cast<const f32x4*>(xrow + d);
        pre[ks][1] = *reinterpret_cast<const f32x4*>(xrow + d + 4);
      } else {
        pre[ks][0] = (f32x4)0.f; pre[ks][1] = (f32x4)0.f;   // stays zero forever
      }
    }
  }

  // ---- weights into registers ----
  // B-frag for xp GEMM: B[k=d][n=h] = Wih[h][d]; lane: h = nt*16+m, d = ks*32+g*8+j
  bf16x8 wihf[4][7];
#pragma unroll
  for (int nt = 0; nt < 4; ++nt) {
    const float* wr = Wih + (size_t)(nt * 16 + m) * DIN;
#pragma unroll
    for (int ks = 0; ks < 7; ++ks) {
      const int d = ks * 32 + g * 8;
      if (d < DIN) {
        f32x4 u0 = *reinterpret_cast<const f32x4*>(wr + d);
        f32x4 u1 = *reinterpret_cast<const f32x4*>(wr + d + 4);
        wihf[nt][ks] = cvt8(u0, u1);
      } else {
        wihf[nt][ks] = (bf16x8)0;
      }
    }
  }
  // B-frag for recurrence: B[k][n=h] = Whh[h][k]; this wave owns n-tile w (h = w*16+m)
  bf16x8 whhf[2];
#pragma unroll
  for (int ks = 0; ks < 2; ++ks) {
    const float* wr = Whh + (size_t)(w * 16 + m) * HID + ks * 32 + g * 8;
    f32x4 u0 = *reinterpret_cast<const f32x4*>(wr);
    f32x4 u1 = *reinterpret_cast<const f32x4*>(wr + 4);
    whhf[ks] = cvt8(u0, u1);
  }
  float bias[4];
#pragma unroll
  for (int nt = 0; nt < 4; ++nt) bias[nt] = bih[nt * 16 + m] + bhh[nt * 16 + m];

  // h_{-1} = 0 lives in buffer 1 (t=0 reads buf[1])
  for (int i = tid; i < NB * 72; i += 256) hbuf[1][0][i] = 0;
  barrier_lds();

  // ---- main loop over 32 chunks of 4 timesteps ----
  for (int c = 0; c < NCH; ++c) {
    // convert this chunk's prefetched x rows to bf16 A-frags (A row = lane&15 = batch row)
    bf16x8 afr[7];
#pragma unroll
    for (int ks = 0; ks < 7; ++ks) afr[ks] = cvt8(pre[ks][0], pre[ks][1]);

    // issue next chunk's global loads now; they stay in flight through the recurrence
    if (c + 1 < NCH) {
      const float* xrow = x + ((size_t)(b0 + m) * TSEQ + ((c + 1) * TC + w)) * DIN;
#pragma unroll
      for (int ks = 0; ks < 7; ++ks) {
        const int d = ks * 32 + g * 8;
        if (d < DIN) {
          pre[ks][0] = *reinterpret_cast<const f32x4*>(xrow + d);
          pre[ks][1] = *reinterpret_cast<const f32x4*>(xrow + d + 4);
        }
      }
    }

    // xp(t = c*TC + w) = x_t * Wih^T + (b_ih + b_hh)
    f32x4 acc[4];
#pragma unroll
    for (int nt = 0; nt < 4; ++nt) acc[nt] = (f32x4)(bias[nt]);
#pragma unroll
    for (int ks = 0; ks < 7; ++ks)
#pragma unroll
      for (int nt = 0; nt < 4; ++nt)
        acc[nt] = __builtin_amdgcn_mfma_f32_16x16x32_bf16(afr[ks], wihf[nt][ks], acc[nt], 0, 0, 0);

    // D layout (m89-verified): col = lane&15 (h), row = (lane>>4)*4 + r (batch)
#pragma unroll
    for (int nt = 0; nt < 4; ++nt)
#pragma unroll
      for (int r = 0; r < 4; ++r)
        xp[w][g * 4 + r][nt * 16 + m] = acc[nt][r];
    barrier_lds();

    // ---- recurrence: h_t = tanh(xp_t + h_{t-1} @ Whh^T), this wave owns h cols w*16..w*16+15
#pragma unroll
    for (int tl = 0; tl < TC; ++tl) {
      const int tt = c * TC + tl;
      const int rb = tt & 1, pb = rb ^ 1;

      // A-frag: H[b = lane&15][k = h'], read 16B per lane per k-step
      bf16x8 ha0 = *reinterpret_cast<const bf16x8*>(&hbuf[pb][m][g * 8]);
      bf16x8 ha1 = *reinterpret_cast<const bf16x8*>(&hbuf[pb][m][32 + g * 8]);

      f32x4 racc;
#pragma unroll
      for (int r = 0; r < 4; ++r) racc[r] = xp[tl][g * 4 + r][w * 16 + m];

      racc = __builtin_amdgcn_mfma_f32_16x16x32_bf16(ha0, whhf[0], racc, 0, 0, 0);
      racc = __builtin_amdgcn_mfma_f32_16x16x32_bf16(ha1, whhf[1], racc, 0, 0, 0);

#pragma unroll
      for (int r = 0; r < 4; ++r) {
        const float hv = fast_tanh(racc[r]);
        hbuf[rb][g * 4 + r][w * 16 + m] = (unsigned short)f2bf(hv);
        if (tt == TSEQ - 1) xp[0][g * 4 + r][w * 16 + m] = hv;   // keep final h in f32
      }
      barrier_lds();
    }
  }

  // ---- epilogue: out[b] = sigmoid(h_last . Wout + bout) ----
  if (tid < 64) {
    const int b = m, q = g;
    float s = 0.f;
#pragma unroll
    for (int j = 0; j < 16; ++j) s += xp[0][b][q * 16 + j] * Wout[q * 16 + j];
    s += __shfl_xor(s, 16, 64);
    s += __shfl_xor(s, 32, 64);
    if (q == 0) {
      const float z = s + bout[0];
      out[b0 + b] = 1.f / (1.f + __expf(-z));
    }
  }
}

extern "C" void kernel_launch(void* const* d_in, const int* in_sizes, int n_in,
                              void* d_out, int out_size, void* d_ws, size_t ws_size,
                              hipStream_t stream) {
  const float* x    = (const float*)d_in[0];
  const float* Wih  = (const float*)d_in[1];
  const float* Whh  = (const float*)d_in[2];
  const float* bih  = (const float*)d_in[3];
  const float* bhh  = (const float*)d_in[4];
  const float* Wout = (const float*)d_in[5];
  const float* bout = (const float*)d_in[6];
  float* out = (float*)d_out;

  const int B = in_sizes[0] / (TSEQ * DIN);   // 4096
  rnn_fused<<<dim3(B / NB), dim3(256), 0, stream>>>(x, Wih, Whh, bih, bhh, Wout, bout, out);
}